// Round 6
// baseline (276.655 us; speedup 1.0000x reference)
//
#include <hip/hip_runtime.h>
#include <math.h>

#define BB 32
#define CC 256
#define HH 64
#define WW 64
#define HWSZ 4096              // HH*WW (one plane)
#define CHW 1048576            // CC*HWSZ

typedef float f4 __attribute__((ext_vector_type(4)));

// ---------------------------------------------------------------------------
// Single fused kernel, one block per (b,h) row, x read EXACTLY ONCE.
//   phase 1: load row (256ch x 64w = 64KB) into registers (16 f4/thread),
//            channel max+mean via LDS combine, publish plane row to ws,
//            device-fence + release flag.
//   phase 2: wave 0 spins (acquire) on flags of rows h-3..h+3 (same b),
//            then computes the 7x7 2->1 conv + sigmoid -> sscale[64] in LDS.
//   phase 3: all threads multiply register-held x by scale, nt-store to out.
// Ticket-based row assignment makes the forward deps dispatch-order-safe:
// tickets are dense among started blocks, every block publishes before it
// waits, deps span <=3 tickets, co-residency >=4 blocks => progress.
// ---------------------------------------------------------------------------
__global__ void __launch_bounds__(256, 3)
sg_fused(const float* __restrict__ x,
         const float* __restrict__ Wt,
         float* __restrict__ out,
         float* __restrict__ maxp,    // [BB*HWSZ]
         float* __restrict__ meanp,   // [BB*HWSZ]
         int* __restrict__ flags,     // [BB*HH], zeroed by prologue memset
         int* __restrict__ ticket) {  // [1], zeroed by prologue memset
    __shared__ int s_row;
    __shared__ float w_sh[98];
    __shared__ alignas(16) float sscale[WW];
    __shared__ f4 lmax[16][16];
    __shared__ f4 lsum[16][16];

    int tid = threadIdx.x;
    if (tid == 0) s_row = atomicAdd(ticket, 1);
    if (tid < 98) w_sh[tid] = Wt[tid];
    __syncthreads();

    const int bh = s_row;
    const int b  = bh >> 6;
    const int h  = bh & 63;
    const int w4 = tid & 15;             // f4 lane within the 64-wide row
    const int cg = tid >> 4;             // 16 channel groups of 16

    const f4* xb =
        reinterpret_cast<const f4*>(x + (size_t)b * CHW + h * WW) + w4;

    // ---- phase 1: load once, reduce ------------------------------------
    f4 xr[16];
    #pragma unroll
    for (int cc = 0; cc < 16; ++cc)
        xr[cc] = __builtin_nontemporal_load(xb + (size_t)(cg * 16 + cc) * 1024);

    f4 mx = xr[0], sm = xr[0];
    #pragma unroll
    for (int cc = 1; cc < 16; ++cc) {
        f4 u = xr[cc];
        mx.x = fmaxf(mx.x, u.x); mx.y = fmaxf(mx.y, u.y);
        mx.z = fmaxf(mx.z, u.z); mx.w = fmaxf(mx.w, u.w);
        sm += u;
    }
    lmax[cg][w4] = mx;
    lsum[cg][w4] = sm;
    __syncthreads();

    if (tid < 16) {
        f4 M = lmax[0][tid];
        f4 S = lsum[0][tid];
        #pragma unroll
        for (int g = 1; g < 16; ++g) {
            f4 m2 = lmax[g][tid];
            S += lsum[g][tid];
            M.x = fmaxf(M.x, m2.x); M.y = fmaxf(M.y, m2.y);
            M.z = fmaxf(M.z, m2.z); M.w = fmaxf(M.w, m2.w);
        }
        reinterpret_cast<f4*>(maxp)[bh * 16 + tid]  = M;
        reinterpret_cast<f4*>(meanp)[bh * 16 + tid] = S * (1.0f / CC);
    }
    __syncthreads();                     // drains this block's vmem writes

    // ---- publish own row, then wait for neighbors ----------------------
    if (tid == 0) {
        __threadfence();                 // agent-scope visibility of planes
        __hip_atomic_store(&flags[bh], 1, __ATOMIC_RELEASE,
                           __HIP_MEMORY_SCOPE_AGENT);
    }
    if (tid < 7) {                       // spinners are in wave 0
        int hh = h - 3 + tid;
        if (hh != h && (unsigned)hh < (unsigned)HH) {
            const int dep = (b << 6) + hh;
            while (__hip_atomic_load(&flags[dep], __ATOMIC_ACQUIRE,
                                     __HIP_MEMORY_SCOPE_AGENT) == 0) {
                __builtin_amdgcn_s_sleep(2);
            }
        }
    }
    __syncthreads();

    // ---- phase 2: 7x7 conv + sigmoid (wave 0 only: same wave that
    //      executed the acquire, so its cache-invalidate covers reads) ----
    if (tid < WW) {
        const float* mb = maxp  + b * HWSZ;
        const float* nb = meanp + b * HWSZ;
        float acc = 0.0f;
        #pragma unroll
        for (int kh = 0; kh < 7; ++kh) {
            int hh = h + kh - 3;
            if ((unsigned)hh >= (unsigned)HH) continue;
            #pragma unroll
            for (int kw = 0; kw < 7; ++kw) {
                int wcol = tid + kw - 3;
                if ((unsigned)wcol >= (unsigned)WW) continue;
                int o = (hh << 6) + wcol;
                acc = fmaf(mb[o], w_sh[kh * 7 + kw],      acc);
                acc = fmaf(nb[o], w_sh[49 + kh * 7 + kw], acc);
            }
        }
        sscale[tid] = 1.0f / (1.0f + __expf(-acc));
    }
    __syncthreads();

    // ---- phase 3: apply from registers, stream out ---------------------
    f4 sc = reinterpret_cast<const f4*>(sscale)[w4];
    f4* ob = reinterpret_cast<f4*>(out + (size_t)b * CHW + h * WW) + w4;
    #pragma unroll
    for (int cc = 0; cc < 16; ++cc) {
        f4 v = xr[cc] * sc;
        __builtin_nontemporal_store(v, ob + (size_t)(cg * 16 + cc) * 1024);
    }
}

extern "C" void kernel_launch(void* const* d_in, const int* in_sizes, int n_in,
                              void* d_out, int out_size, void* d_ws, size_t ws_size,
                              hipStream_t stream) {
    const float* x  = (const float*)d_in[0];   // [32,256,64,64]
    const float* Wt = (const float*)d_in[1];   // [1,2,7,7] = 98 floats
    float* out = (float*)d_out;

    float* wsf   = (float*)d_ws;
    float* maxp  = wsf;                        // 131072 floats
    float* meanp = wsf + BB * HWSZ;            // 131072 floats
    int*   flags = (int*)(wsf + 2 * BB * HWSZ);// 2048 ints
    int*   ticket = flags + BB * HH;           // 1 int

    // zero flags + ticket every call (replays reuse ws)
    hipMemsetAsync(flags, 0, (BB * HH + 1) * sizeof(int), stream);

    sg_fused<<<BB * HH, 256, 0, stream>>>(x, Wt, out, maxp, meanp, flags, ticket);
}

// Round 10
// 72.095 us; speedup vs baseline: 3.8374x; 3.8374x over previous
//
#include <hip/hip_runtime.h>
#include <math.h>

#define BB 32
#define CC 256
#define HH 64
#define WW 64
#define HWSZ 4096              // HH*WW (one plane)
#define CHW 1048576            // CC*HWSZ

typedef float f4 __attribute__((ext_vector_type(4)));
typedef unsigned long long u64;

__device__ __forceinline__ u64 pack2(float mx, float mn) {
    return ((u64)__float_as_uint(mn) << 32) | (u64)__float_as_uint(mx);
}

// ---------------------------------------------------------------------------
// Single fused kernel, one block per (b,h) row, x read EXACTLY ONCE from HBM.
// All cross-block communication via RETURNING atomic RMWs (return value kept
// live). Returning RMWs cannot ack vmcnt until the data comes back from the
// device coherence point, so:
//   publish planes : atomicExch(u64) with consumed return  -> globally done
//   __syncthreads  : vmcnt(0) per wave -> planes performed before...
//   publish flag   : atomicExch(int)
//   poll flag      : atomicAdd(&f, 0)        (returning by construction)
//   read halo      : atomicAdd(&p, 0ULL)     (returning by construction)
// This fixes R7 (reader XCD caching stale ws-poison across graph replays)
// AND R8 (non-returning exch overtaking the flag through the fabric).
// (max,mean) packed per pixel in one u64 -> half the MALL round-trips.
// Ticket-based row assignment: publish-before-wait, deps span <=3 tickets,
// ~512 co-resident blocks => progress under any dispatch order.
// ---------------------------------------------------------------------------
__global__ void __launch_bounds__(256, 2)
sg_fused(const float* __restrict__ x,
         const float* __restrict__ Wt,
         float* __restrict__ out,
         u64* plane,                  // [BB*HWSZ] packed (max,mean)
         int* flags,                  // [BB*HH], zeroed by prologue memset
         int* ticket) {               // [1], zeroed by prologue memset
    __shared__ int s_row;
    __shared__ float w_sh[98];
    __shared__ alignas(16) float sscale[WW];
    __shared__ f4 lmax[16][16];
    __shared__ f4 lsum[16][16];
    __shared__ float s_halo[2][7][WW];   // [plane][krow][col]

    int tid = threadIdx.x;
    if (tid == 0) s_row = atomicAdd(ticket, 1);
    if (tid < 98) w_sh[tid] = Wt[tid];
    __syncthreads();

    const int bh = s_row;
    const int b  = bh >> 6;
    const int h  = bh & 63;
    const int w4 = tid & 15;             // f4 lane within the 64-wide row
    const int cg = tid >> 4;             // 16 channel groups of 16

    const f4* xb =
        reinterpret_cast<const f4*>(x + (size_t)b * CHW + h * WW) + w4;

    // ---- phase 1: load x once (cached; L3 retains x across replays) -----
    f4 xr[16];
    #pragma unroll
    for (int cc = 0; cc < 16; ++cc)
        xr[cc] = xb[(size_t)(cg * 16 + cc) * 1024];

    f4 mx = xr[0], sm = xr[0];
    #pragma unroll
    for (int cc = 1; cc < 16; ++cc) {
        f4 u = xr[cc];
        mx.x = fmaxf(mx.x, u.x); mx.y = fmaxf(mx.y, u.y);
        mx.z = fmaxf(mx.z, u.z); mx.w = fmaxf(mx.w, u.w);
        sm += u;
    }
    lmax[cg][w4] = mx;
    lsum[cg][w4] = sm;
    __syncthreads();

    if (tid < 16) {
        f4 M = lmax[0][tid];
        f4 S = lsum[0][tid];
        #pragma unroll
        for (int g = 1; g < 16; ++g) {
            f4 m2 = lmax[g][tid];
            S += lsum[g][tid];
            M.x = fmaxf(M.x, m2.x); M.y = fmaxf(M.y, m2.y);
            M.z = fmaxf(M.z, m2.z); M.w = fmaxf(M.w, m2.w);
        }
        f4 MN = S * (1.0f / CC);
        u64* pp = plane + (size_t)bh * WW + tid * 4;
        u64 sink = 0;
        #pragma unroll
        for (int j = 0; j < 4; ++j) {
            // RETURNING exch: consume old value so sc0 variant is emitted
            sink ^= atomicExch(pp + j, pack2(M[j], MN[j]));
        }
        asm volatile("" :: "v"(sink));   // keep returns live (no DCE)
    }
    __syncthreads();                     // vmcnt(0): plane RMWs performed

    // ---- publish own flag, then wait for neighbors (returning polls) ----
    if (tid == 0)
        (void)atomicExch(&flags[bh], 1);
    if (tid < 7) {
        int hh = h - 3 + tid;
        if (hh != h && (unsigned)hh < (unsigned)HH) {
            int* dep = &flags[(b << 6) + hh];
            while (atomicAdd(dep, 0) == 0) {
                __builtin_amdgcn_s_sleep(8);
            }
        }
    }
    __syncthreads();

    // ---- halo: returning RMW reads (coherence point) into LDS -----------
    // 7 rows x 64 cols = 448 u64; 256 threads x 2 rounds.
    #pragma unroll
    for (int k = 0; k < 2; ++k) {
        int idx = tid + k * 256;
        if (idx < 7 * WW) {
            int r  = idx >> 6;
            int c  = idx & 63;
            int hh = h - 3 + r;
            u64 v  = 0;
            if ((unsigned)hh < (unsigned)HH)
                v = atomicAdd(plane + (size_t)((b << 6) + hh) * WW + c, 0ULL);
            s_halo[0][r][c] = __uint_as_float((unsigned)(v & 0xFFFFFFFFu));
            s_halo[1][r][c] = __uint_as_float((unsigned)(v >> 32));
        }
    }
    __syncthreads();

    // ---- phase 2: 7x7 conv + sigmoid from LDS ---------------------------
    if (tid < WW) {
        float acc = 0.0f;
        #pragma unroll
        for (int kh = 0; kh < 7; ++kh) {
            #pragma unroll
            for (int kw = 0; kw < 7; ++kw) {
                int wcol = tid + kw - 3;
                if ((unsigned)wcol >= (unsigned)WW) continue;
                acc = fmaf(s_halo[0][kh][wcol], w_sh[kh * 7 + kw],      acc);
                acc = fmaf(s_halo[1][kh][wcol], w_sh[49 + kh * 7 + kw], acc);
            }
        }
        sscale[tid] = 1.0f / (1.0f + __expf(-acc));
    }
    __syncthreads();

    // ---- phase 3: apply from registers, nt-store out --------------------
    f4 sc = reinterpret_cast<const f4*>(sscale)[w4];
    f4* ob = reinterpret_cast<f4*>(out + (size_t)b * CHW + h * WW) + w4;
    #pragma unroll
    for (int cc = 0; cc < 16; ++cc) {
        f4 v = xr[cc] * sc;
        __builtin_nontemporal_store(v, ob + (size_t)(cg * 16 + cc) * 1024);
    }
}

extern "C" void kernel_launch(void* const* d_in, const int* in_sizes, int n_in,
                              void* d_out, int out_size, void* d_ws, size_t ws_size,
                              hipStream_t stream) {
    const float* x  = (const float*)d_in[0];   // [32,256,64,64]
    const float* Wt = (const float*)d_in[1];   // [1,2,7,7] = 98 floats
    float* out = (float*)d_out;

    u64* plane   = (u64*)d_ws;                 // 131072 u64 (1 MB)
    int* flags   = (int*)(plane + (size_t)BB * HWSZ);  // 2048 ints
    int* ticket  = flags + BB * HH;            // 1 int

    // zero flags + ticket every call (kernel-end release of the fill kernel
    // makes the zeros globally visible before sg_fused's RMWs run; sg_fused
    // touches them only via RMW afterwards).
    hipMemsetAsync(flags, 0, (BB * HH + 1) * sizeof(int), stream);

    sg_fused<<<BB * HH, 256, 0, stream>>>(x, Wt, out, plane, flags, ticket);
}